// Round 5
// baseline (1168.596 us; speedup 1.0000x reference)
//
#include <hip/hip_runtime.h>
#include <hip/hip_bf16.h>
#include <stdint.h>

typedef __bf16 bf16_t;
typedef __bf16 bf16x8 __attribute__((ext_vector_type(8)));
typedef __bf16 bf16x4 __attribute__((ext_vector_type(4)));
typedef float f32x4 __attribute__((ext_vector_type(4)));

// Problem constants: B=32, H=W=64, C=256, heads=8, ws=8, ss=4
#define MROWS 131072   // B * 64 * 64 tokens (window layout rows)

__device__ __forceinline__ bf16_t to_bf16(float f) {
  __hip_bfloat16 h = __float2bfloat16(f);   // RNE
  return *reinterpret_cast<bf16_t*>(&h);
}

__device__ __forceinline__ f32x4 mfma16(bf16x8 a, bf16x8 b, f32x4 c) {
  return __builtin_amdgcn_mfma_f32_16x16x32_bf16(a, b, c, 0, 0, 0);
}

__device__ __forceinline__ void gload16(const void* g, void* l) {
  __builtin_amdgcn_global_load_lds(
      (const __attribute__((address_space(1))) void*)g,
      (__attribute__((address_space(3))) void*)l, 16, 0, 0);
}

// window-layout row m  ->  x row (shift+partition gather; reverse+unshift scatter)
__device__ __forceinline__ int map_row(int m) {
  int b   = m >> 12;
  int rem = m & 4095;
  int win = rem >> 6;
  int n   = rem & 63;
  int gh  = ((win >> 3) << 3) + (n >> 3);
  int gw  = ((win & 7) << 3) + (n & 7);
  int sh  = (gh + 4) & 63;
  int sw  = (gw + 4) & 63;
  return (b << 12) + (sh << 6) + sw;
}

// ---------------- fp32 -> bf16 weight convert ----------------
__global__ __launch_bounds__(256) void cvt_kernel(const float* __restrict__ in,
                                                  bf16_t* __restrict__ out, int n) {
  int i = blockIdx.x * 256 + threadIdx.x;
  if (i < n) out[i] = to_bf16(in[i]);
}

// ---------------- bias table: bias[cls][h][n][m] = rpb(n,m,h) + mask(cls,n,m) ----------------
__global__ __launch_bounds__(256) void bias_kernel(const float* __restrict__ rpbt,
                                                   float* __restrict__ bias) {
  int idx = blockIdx.x * 256 + threadIdx.x;   // 0 .. 131071
  int m = idx & 63, n = (idx >> 6) & 63, h = (idx >> 12) & 7, c = idx >> 15;
  int yn = n >> 3, xn = n & 7, ym = m >> 3, xm = m & 7;
  float v = rpbt[((yn - ym + 7) * 15 + (xn - xm + 7)) * 8 + h];
  int rn = (c & 2) ? (yn < 4 ? 1 : 2) : 0;
  int cn = (c & 1) ? (xn < 4 ? 1 : 2) : 0;
  int rm = (c & 2) ? (ym < 4 ? 1 : 2) : 0;
  int cm = (c & 1) ? (xm < 4 ? 1 : 2) : 0;
  if (rn * 3 + cn != rm * 3 + cm) v -= 100.0f;
  bias[idx] = v;
}

// ---------------- LayerNorm (wave per row), optional row-permuted gather ----------------
template <bool PERM>
__global__ __launch_bounds__(256) void ln_kernel(const float* __restrict__ xin,
                                                 const float* __restrict__ g,
                                                 const float* __restrict__ b,
                                                 bf16_t* __restrict__ out) {
  int row  = (blockIdx.x << 2) + (threadIdx.x >> 6);
  int lane = threadIdx.x & 63;
  int src  = PERM ? map_row(row) : row;
  float4 v = *reinterpret_cast<const float4*>(xin + (size_t)src * 256 + (lane << 2));
  float s = v.x + v.y + v.z + v.w;
#pragma unroll
  for (int d = 1; d < 64; d <<= 1) s += __shfl_xor(s, d);
  float mean = s * 0.00390625f;
  float ax = v.x - mean, ay = v.y - mean, az = v.z - mean, aw = v.w - mean;
  float s2 = ax * ax + ay * ay + az * az + aw * aw;
#pragma unroll
  for (int d = 1; d < 64; d <<= 1) s2 += __shfl_xor(s2, d);
  float rstd = rsqrtf(s2 * 0.00390625f + 1e-5f);
  float4 gv = *reinterpret_cast<const float4*>(g + (lane << 2));
  float4 bv = *reinterpret_cast<const float4*>(b + (lane << 2));
  bf16x4 o4;
  o4[0] = to_bf16(ax * rstd * gv.x + bv.x);
  o4[1] = to_bf16(ay * rstd * gv.y + bv.y);
  o4[2] = to_bf16(az * rstd * gv.z + bv.z);
  o4[3] = to_bf16(aw * rstd * gv.w + bv.w);
  *reinterpret_cast<bf16x4*>(out + (size_t)row * 256 + (lane << 2)) = o4;
}

// ---------------- QKV: A-resident GEMM. A tile 128 x 256 (full K) staged ONCE
// (gload_lds, XOR-swizzled source), one barrier, then 6 free-running n-blocks.
// Output split head-major: {q,k,v}[h][row][32] bf16.
__global__ __launch_bounds__(256) void qkv_ares(const bf16_t* __restrict__ A,
                                                const bf16_t* __restrict__ W,
                                                const float* __restrict__ bias,
                                                bf16_t* __restrict__ q,
                                                bf16_t* __restrict__ k,
                                                bf16_t* __restrict__ v) {
  extern __shared__ __align__(16) char smem_raw[];
  bf16_t* As = (bf16_t*)smem_raw;           // [128][256] linear, source-swizzled
  const int tid = threadIdx.x;
  const int lane = tid & 63, lo = lane & 15, hi = lane >> 4;
  const int wave = tid >> 6;
  const int bm = blockIdx.x << 7;
  const int wr = (wave >> 1) << 6, wc = (wave & 1) << 6;

  // stage 4096 x 16B chunks; LDS linear, source chunk g = c ^ ((c>>5)&7)
#pragma unroll
  for (int it = 0; it < 16; ++it) {
    int c = (it << 8) + tid;
    int g = c ^ ((c >> 5) & 7);
    gload16(A + (size_t)(bm + (c >> 5)) * 256 + ((g & 31) << 3), &As[c << 3]);
  }
  __syncthreads();

  for (int nbp = 0; nbp < 3; ++nbp) {       // pairs of 128-col n-blocks
    f32x4 acc[2][4][4] = {};
    for (int kk = 0; kk < 8; ++kk) {
      bf16x8 af[4];
#pragma unroll
      for (int i = 0; i < 4; ++i) {
        int row = wr + (i << 4) + lo;
        af[i] = *reinterpret_cast<const bf16x8*>(
            &As[row * 256 + ((((kk << 2) + hi) ^ (row & 7)) << 3)]);
      }
#pragma unroll
      for (int half = 0; half < 2; ++half) {
        int bn = (nbp << 8) + (half << 7);
        bf16x8 wf[4];
#pragma unroll
        for (int j = 0; j < 4; ++j)
          wf[j] = *reinterpret_cast<const bf16x8*>(
              W + (size_t)(bn + wc + (j << 4) + lo) * 256 + (kk << 5) + (hi << 3));
#pragma unroll
        for (int i = 0; i < 4; ++i)
#pragma unroll
          for (int j = 0; j < 4; ++j)
            acc[half][i][j] = mfma16(af[i], wf[j], acc[half][i][j]);
      }
    }
#pragma unroll
    for (int half = 0; half < 2; ++half) {
      int bn = (nbp << 8) + (half << 7);
#pragma unroll
      for (int j = 0; j < 4; ++j) {
        int col = bn + wc + (j << 4) + lo;   // 0..767
        float bv = bias[col];
        bf16_t* base = (col < 256) ? q : (col < 512) ? k : v;
        int hd = (col >> 5) & 7, d = col & 31;
#pragma unroll
        for (int i = 0; i < 4; ++i)
#pragma unroll
          for (int r = 0; r < 4; ++r) {
            int row = bm + wr + (i << 4) + (hi << 2) + r;
            base[((size_t)hd * MROWS + row) * 32 + d] = to_bf16(acc[half][i][j][r] + bv);
          }
      }
    }
  }
}

// ---------------- windowed attention: one wave per (window, head)  [round-2 proven] ----
// qh,kh,vh: head-major [8][131072][32] bf16; o: token-major [131072][256] bf16
__global__ __launch_bounds__(256) void attn_kernel(const bf16_t* __restrict__ qh,
                                                   const bf16_t* __restrict__ kh,
                                                   const bf16_t* __restrict__ vh,
                                                   const float* __restrict__ bias,
                                                   bf16_t* __restrict__ o) {
  __shared__ __align__(16) bf16_t Pl[4][64 * 72];
  __shared__ __align__(16) bf16_t Vt[4][32 * 72];
  const int wave = threadIdx.x >> 6, lane = threadIdx.x & 63;
  const int lo = lane & 15, hi = lane >> 4;
  const int id = (blockIdx.x << 2) + wave;  // 0..16383
  const int win = id >> 3, h = id & 7;
  const size_t hb = ((size_t)h * MROWS + (size_t)win * 64) * 32;
  const bf16_t* qb = qh + hb;
  const bf16_t* kb = kh + hb;
  const bf16_t* vb = vh + hb;

  // stage V transposed into LDS: Vt[d][m], stride 72 (coalesced 16B reads)
  const bf16_t* vbl = vb + lane * 32;
#pragma unroll
  for (int c4 = 0; c4 < 4; ++c4) {
    bf16x8 v8 = *reinterpret_cast<const bf16x8*>(vbl + (c4 << 3));
#pragma unroll
    for (int e = 0; e < 8; ++e) Vt[wave][((c4 << 3) + e) * 72 + lane] = v8[e];
  }

  // QK^T (K-dim = 32 = one mfma step); coalesced fragment loads
  bf16x8 qa[4], ka[4];
#pragma unroll
  for (int i = 0; i < 4; ++i)
    qa[i] = *reinterpret_cast<const bf16x8*>(qb + ((i << 4) + lo) * 32 + (hi << 3));
#pragma unroll
  for (int j = 0; j < 4; ++j)
    ka[j] = *reinterpret_cast<const bf16x8*>(kb + ((j << 4) + lo) * 32 + (hi << 3));
  f32x4 s[4][4] = {};
#pragma unroll
  for (int i = 0; i < 4; ++i)
#pragma unroll
    for (int j = 0; j < 4; ++j) s[i][j] = mfma16(qa[i], ka[j], s[i][j]);

  const int wh = (win & 63) >> 3, ww = win & 7;
  const int cls = ((wh == 7) ? 2 : 0) + ((ww == 7) ? 1 : 0);
  const float* bb = bias + ((size_t)cls * 8 + h) * 4096;
  const float scale = 0.17677669529663687f;  // 1/sqrt(32)

  float pinv[4][4];
#pragma unroll
  for (int i = 0; i < 4; ++i) {
#pragma unroll
    for (int r = 0; r < 4; ++r) {
      int n = (i << 4) + (hi << 2) + r;
      const float* brow = bb + n * 64 + lo;
      float vals[4], mx = -1e30f;
#pragma unroll
      for (int j = 0; j < 4; ++j) {
        float val = s[i][j][r] * scale + brow[j << 4];
        vals[j] = val;
        mx = fmaxf(mx, val);
      }
#pragma unroll
      for (int d = 1; d < 16; d <<= 1) mx = fmaxf(mx, __shfl_xor(mx, d));
      float sum = 0.0f;
#pragma unroll
      for (int j = 0; j < 4; ++j) {
        float p = __expf(vals[j] - mx);
        sum += p;
        Pl[wave][n * 72 + (j << 4) + lo] = to_bf16(p);
      }
#pragma unroll
      for (int d = 1; d < 16; d <<= 1) sum += __shfl_xor(sum, d);
      pinv[i][r] = 1.0f / sum;
    }
  }

  __syncthreads();   // Vt + Pl cross-lane LDS visibility

  // PV: O[64,32] = P[64,64] @ V[64,32]
  f32x4 oa[4][2] = {};
#pragma unroll
  for (int kt = 0; kt < 2; ++kt) {
    bf16x8 pa[4], va[2];
#pragma unroll
    for (int i = 0; i < 4; ++i)
      pa[i] = *reinterpret_cast<const bf16x8*>(&Pl[wave][((i << 4) + lo) * 72 + (kt << 5) + (hi << 3)]);
#pragma unroll
    for (int dt = 0; dt < 2; ++dt)
      va[dt] = *reinterpret_cast<const bf16x8*>(&Vt[wave][((dt << 4) + lo) * 72 + (kt << 5) + (hi << 3)]);
#pragma unroll
    for (int i = 0; i < 4; ++i)
#pragma unroll
      for (int dt = 0; dt < 2; ++dt) oa[i][dt] = mfma16(pa[i], va[dt], oa[i][dt]);
  }

  bf16_t* ob = o + (size_t)win * (64 * 256) + h * 32;
#pragma unroll
  for (int i = 0; i < 4; ++i)
#pragma unroll
    for (int r = 0; r < 4; ++r) {
      int n = (i << 4) + (hi << 2) + r;
      float piv = pinv[i][r];
#pragma unroll
      for (int dt = 0; dt < 2; ++dt)
        ob[(size_t)n * 256 + (dt << 4) + lo] = to_bf16(oa[i][dt][r] * piv);
    }
}

// ---------------- proj GEMM (m97 structure) + window-reverse scatter + residual [round-2 proven]
__global__ __launch_bounds__(256) void gemm_proj(const bf16_t* __restrict__ A,
                                                 const bf16_t* __restrict__ W,
                                                 const float* __restrict__ bias,
                                                 float* __restrict__ out,
                                                 const float* __restrict__ resid) {
  __shared__ __align__(16) bf16_t As[128 * 32];
  __shared__ __align__(16) bf16_t Bs[128 * 32];
  const int tid  = threadIdx.x;
  const int lane = tid & 63, lo = lane & 15, hi = lane >> 4;
  const int wave = tid >> 6;
  const int bm = blockIdx.x << 7, bn = blockIdx.y << 7;
  const int wr = (wave >> 1) << 6, wc = (wave & 1) << 6;
  f32x4 acc[4][4] = {};

  for (int k0 = 0; k0 < 256; k0 += 32) {
    __syncthreads();
#pragma unroll
    for (int it = 0; it < 2; ++it) {
      int ch = (it << 8) + tid;
      int r = ch >> 2, kf = (ch & 3) << 3;
      gload16(A + (size_t)(bm + r) * 256 + (k0 + kf), &As[ch << 3]);
      gload16(W + (size_t)(bn + r) * 256 + (k0 + kf), &Bs[ch << 3]);
    }
    __syncthreads();
    bf16x8 af[4], bfr[4];
#pragma unroll
    for (int i = 0; i < 4; ++i)
      af[i] = *reinterpret_cast<const bf16x8*>(&As[(wr + (i << 4) + lo) * 32 + (hi << 3)]);
#pragma unroll
    for (int j = 0; j < 4; ++j)
      bfr[j] = *reinterpret_cast<const bf16x8*>(&Bs[(wc + (j << 4) + lo) * 32 + (hi << 3)]);
#pragma unroll
    for (int i = 0; i < 4; ++i)
#pragma unroll
      for (int j = 0; j < 4; ++j)
        acc[i][j] = mfma16(af[i], bfr[j], acc[i][j]);
  }

  float bv[4];
#pragma unroll
  for (int j = 0; j < 4; ++j) bv[j] = bias[bn + wc + (j << 4) + lo];

#pragma unroll
  for (int i = 0; i < 4; ++i)
#pragma unroll
    for (int r = 0; r < 4; ++r) {
      int row = bm + wr + (i << 4) + (hi << 2) + r;
      int xr = map_row(row);
#pragma unroll
      for (int j = 0; j < 4; ++j) {
        int col = bn + wc + (j << 4) + lo;
        size_t idx = (size_t)xr * 256 + col;
        out[idx] = resid[idx] + acc[i][j][r] + bv[j];
      }
    }
}

// ---------------- fused MLP: out += GELU(x2n @ W1^T + b1) @ W2^T + b2 ----------------
// Block = 64 rows. A staged once (swizzled gload_lds); 4 h-chunks of 256 cols:
// FC1 -> GELU -> Hs (LDS) -> FC2 accumulate into persistent acc2. One fp32 += epilogue.
__global__ __launch_bounds__(256) void mlp_fused(const bf16_t* __restrict__ A,
                                                 const bf16_t* __restrict__ W1,
                                                 const float* __restrict__ b1,
                                                 const bf16_t* __restrict__ W2,
                                                 const float* __restrict__ b2,
                                                 float* __restrict__ out) {
  extern __shared__ __align__(16) char smem_raw[];
  bf16_t* As = (bf16_t*)smem_raw;           // [64][256] linear, source-swizzled
  bf16_t* Hs = As + 16384;                  // [64][264] padded
  const int tid = threadIdx.x;
  const int lane = tid & 63, lo = lane & 15, hi = lane >> 4;
  const int wave = tid >> 6;
  const int bm = blockIdx.x << 6;           // 64 rows
  const int wr = (wave >> 1) << 5;          // 0 | 32
  const int wc = (wave & 1) << 7;           // 0 | 128

#pragma unroll
  for (int it = 0; it < 8; ++it) {
    int c = (it << 8) + tid;
    int g = c ^ ((c >> 5) & 7);
    gload16(A + (size_t)(bm + (c >> 5)) * 256 + ((g & 31) << 3), &As[c << 3]);
  }
  __syncthreads();

  f32x4 acc2[2][8] = {};
  for (int nc = 0; nc < 4; ++nc) {
    // FC1 chunk: h[rows wr..wr+32][cols wc..wc+128] of h-block nc
    f32x4 acc1[2][8] = {};
    for (int kk = 0; kk < 8; ++kk) {
      bf16x8 af[2];
#pragma unroll
      for (int i = 0; i < 2; ++i) {
        int row = wr + (i << 4) + lo;
        af[i] = *reinterpret_cast<const bf16x8*>(
            &As[row * 256 + ((((kk << 2) + hi) ^ (row & 7)) << 3)]);
      }
#pragma unroll
      for (int j = 0; j < 8; ++j) {
        bf16x8 wf = *reinterpret_cast<const bf16x8*>(
            W1 + (size_t)((nc << 8) + wc + (j << 4) + lo) * 256 + (kk << 5) + (hi << 3));
#pragma unroll
        for (int i = 0; i < 2; ++i) acc1[i][j] = mfma16(af[i], wf, acc1[i][j]);
      }
    }
    // GELU (exact) -> Hs
#pragma unroll
    for (int j = 0; j < 8; ++j) {
      float bb = b1[(nc << 8) + wc + (j << 4) + lo];
#pragma unroll
      for (int i = 0; i < 2; ++i)
#pragma unroll
        for (int r = 0; r < 4; ++r) {
          int row = wr + (i << 4) + (hi << 2) + r;
          float vv = acc1[i][j][r] + bb;
          vv = 0.5f * vv * (1.0f + erff(vv * 0.70710678118654752f));
          Hs[row * 264 + wc + (j << 4) + lo] = to_bf16(vv);
        }
    }
    __syncthreads();
    // FC2: acc2 += Hchunk @ W2chunk^T
    for (int kk = 0; kk < 8; ++kk) {
      bf16x8 hf[2];
#pragma unroll
      for (int i = 0; i < 2; ++i)
        hf[i] = *reinterpret_cast<const bf16x8*>(
            &Hs[(wr + (i << 4) + lo) * 264 + (kk << 5) + (hi << 3)]);
#pragma unroll
      for (int j = 0; j < 8; ++j) {
        bf16x8 wf = *reinterpret_cast<const bf16x8*>(
            W2 + (size_t)(wc + (j << 4) + lo) * 1024 + (nc << 8) + (kk << 5) + (hi << 3));
#pragma unroll
        for (int i = 0; i < 2; ++i) acc2[i][j] = mfma16(hf[i], wf, acc2[i][j]);
      }
    }
    __syncthreads();
  }

#pragma unroll
  for (int j = 0; j < 8; ++j) {
    float bb = b2[wc + (j << 4) + lo];
#pragma unroll
    for (int i = 0; i < 2; ++i)
#pragma unroll
      for (int r = 0; r < 4; ++r) {
        int row = bm + wr + (i << 4) + (hi << 2) + r;
        size_t idx = (size_t)row * 256 + wc + (j << 4) + lo;
        out[idx] = out[idx] + acc2[i][j][r] + bb;
      }
  }
}

// ---------------- launch ----------------
extern "C" void kernel_launch(void* const* d_in, const int* in_sizes, int n_in,
                              void* d_out, int out_size, void* d_ws, size_t ws_size,
                              hipStream_t stream) {
  const float* x      = (const float*)d_in[0];
  const float* n1g    = (const float*)d_in[1];
  const float* n1b    = (const float*)d_in[2];
  const float* qkv_w  = (const float*)d_in[3];
  const float* qkv_b  = (const float*)d_in[4];
  const float* rpbt   = (const float*)d_in[5];
  const float* proj_w = (const float*)d_in[6];
  const float* proj_b = (const float*)d_in[7];
  const float* n2g    = (const float*)d_in[8];
  const float* n2b    = (const float*)d_in[9];
  const float* fc1_w  = (const float*)d_in[10];
  const float* fc1_b  = (const float*)d_in[11];
  const float* fc2_w  = (const float*)d_in[12];
  const float* fc2_b  = (const float*)d_in[13];
  float* out = (float*)d_out;
  char*  ws  = (char*)d_ws;

  // ws: [0,64Mi) hln -> obuf | [64Mi,128Mi) qbuf -> x2n | [128Mi..] weights+bias
  // d_out: k,v bf16 (head-major) until proj, then x2/out fp32.
  const size_t MB64 = 67108864;
  bf16_t* hln  = (bf16_t*)(ws);
  bf16_t* obuf = (bf16_t*)(ws);
  bf16_t* qbuf = (bf16_t*)(ws + MB64);
  bf16_t* x2n  = (bf16_t*)(ws + MB64);
  bf16_t* wb   = (bf16_t*)(ws + 2 * MB64);
  bf16_t* qkv_wb  = wb;                   // 196608 el
  bf16_t* proj_wb = qkv_wb + 196608;      // 65536
  bf16_t* fc1_wb  = proj_wb + 65536;      // 262144
  bf16_t* fc2_wb  = fc1_wb + 262144;      // 262144
  float*  biast   = (float*)(fc2_wb + 262144);  // 131072 f32 = 512KB
  bf16_t* kbuf = (bf16_t*)d_out;          // 33554432 el (64MiB)
  bf16_t* vbuf = kbuf + 33554432;

  hipFuncSetAttribute(reinterpret_cast<const void*>(qkv_ares),
                      hipFuncAttributeMaxDynamicSharedMemorySize, 65536);
  hipFuncSetAttribute(reinterpret_cast<const void*>(mlp_fused),
                      hipFuncAttributeMaxDynamicSharedMemorySize, 66560);

  cvt_kernel<<<768, 256, 0, stream>>>(qkv_w, qkv_wb, 196608);
  cvt_kernel<<<256, 256, 0, stream>>>(proj_w, proj_wb, 65536);
  cvt_kernel<<<1024, 256, 0, stream>>>(fc1_w, fc1_wb, 262144);
  cvt_kernel<<<1024, 256, 0, stream>>>(fc2_w, fc2_wb, 262144);
  bias_kernel<<<512, 256, 0, stream>>>(rpbt, biast);

  // LN1 + shift + window partition
  ln_kernel<true><<<32768, 256, 0, stream>>>(x, n1g, n1b, hln);

  // QKV (A-resident) -> head-major q/k/v
  qkv_ares<<<1024, 256, 65536, stream>>>(hln, qkv_wb, qkv_b, qbuf, kbuf, vbuf);

  // windowed attention
  attn_kernel<<<4096, 256, 0, stream>>>(qbuf, kbuf, vbuf, biast, obuf);

  // proj + window-reverse + unshift + residual -> x2 fp32 in d_out
  gemm_proj<<<dim3(1024, 2), 256, 0, stream>>>(obuf, proj_wb, proj_b, out, x);

  // LN2
  ln_kernel<false><<<32768, 256, 0, stream>>>(out, n2g, n2b, x2n);

  // fused MLP: out += GELU(x2n@W1^T+b1)@W2^T + b2
  mlp_fused<<<2048, 256, 66560, stream>>>(x2n, fc1_wb, fc1_b, fc2_wb, fc2_b, out);
}

// Round 6
// 667.999 us; speedup vs baseline: 1.7494x; 1.7494x over previous
//
#include <hip/hip_runtime.h>
#include <hip/hip_bf16.h>
#include <stdint.h>

typedef __bf16 bf16_t;
typedef __bf16 bf16x8 __attribute__((ext_vector_type(8)));
typedef __bf16 bf16x4 __attribute__((ext_vector_type(4)));
typedef float f32x4 __attribute__((ext_vector_type(4)));

// Problem constants: B=32, H=W=64, C=256, heads=8, ws=8, ss=4
#define MROWS 131072   // B * 64 * 64 tokens (window layout rows)

__device__ __forceinline__ bf16_t to_bf16(float f) {
  __hip_bfloat16 h = __float2bfloat16(f);   // RNE
  return *reinterpret_cast<bf16_t*>(&h);
}

__device__ __forceinline__ f32x4 mfma16(bf16x8 a, bf16x8 b, f32x4 c) {
  return __builtin_amdgcn_mfma_f32_16x16x32_bf16(a, b, c, 0, 0, 0);
}

__device__ __forceinline__ void gload16(const void* g, void* l) {
  __builtin_amdgcn_global_load_lds(
      (const __attribute__((address_space(1))) void*)g,
      (__attribute__((address_space(3))) void*)l, 16, 0, 0);
}

// window-layout row m  ->  x row (shift+partition gather; reverse+unshift scatter)
__device__ __forceinline__ int map_row(int m) {
  int b   = m >> 12;
  int rem = m & 4095;
  int win = rem >> 6;
  int n   = rem & 63;
  int gh  = ((win >> 3) << 3) + (n >> 3);
  int gw  = ((win & 7) << 3) + (n & 7);
  int sh  = (gh + 4) & 63;
  int sw  = (gw + 4) & 63;
  return (b << 12) + (sh << 6) + sw;
}

// ---------------- fp32 -> bf16 weight convert (all 4 weight mats, one launch) ------
__global__ __launch_bounds__(256) void cvt_all(const float* __restrict__ qkv_w,
                                               const float* __restrict__ proj_w,
                                               const float* __restrict__ fc1_w,
                                               const float* __restrict__ fc2_w,
                                               bf16_t* __restrict__ qkv_o,
                                               bf16_t* __restrict__ proj_o,
                                               bf16_t* __restrict__ fc1_o,
                                               bf16_t* __restrict__ fc2_o) {
  int i = blockIdx.x * 256 + threadIdx.x;   // 0 .. 786431
  if (i < 196608)       qkv_o[i] = to_bf16(qkv_w[i]);
  else if (i < 262144)  proj_o[i - 196608] = to_bf16(proj_w[i - 196608]);
  else if (i < 524288)  fc1_o[i - 262144] = to_bf16(fc1_w[i - 262144]);
  else                  fc2_o[i - 524288] = to_bf16(fc2_w[i - 524288]);
}

// ---------------- bias table: bias[cls][h][n][m] = rpb(n,m,h) + mask(cls,n,m) ------
__global__ __launch_bounds__(256) void bias_kernel(const float* __restrict__ rpbt,
                                                   float* __restrict__ bias) {
  int idx = blockIdx.x * 256 + threadIdx.x;   // 0 .. 131071
  int m = idx & 63, n = (idx >> 6) & 63, h = (idx >> 12) & 7, c = idx >> 15;
  int yn = n >> 3, xn = n & 7, ym = m >> 3, xm = m & 7;
  float v = rpbt[((yn - ym + 7) * 15 + (xn - xm + 7)) * 8 + h];
  int rn = (c & 2) ? (yn < 4 ? 1 : 2) : 0;
  int cn = (c & 1) ? (xn < 4 ? 1 : 2) : 0;
  int rm = (c & 2) ? (ym < 4 ? 1 : 2) : 0;
  int cm = (c & 1) ? (xm < 4 ? 1 : 2) : 0;
  if (rn * 3 + cn != rm * 3 + cm) v -= 100.0f;
  bias[idx] = v;
}

// ---------------- LayerNorm (wave per row), optional row-permuted gather ----------------
template <bool PERM>
__global__ __launch_bounds__(256) void ln_kernel(const float* __restrict__ xin,
                                                 const float* __restrict__ g,
                                                 const float* __restrict__ b,
                                                 bf16_t* __restrict__ out) {
  int row  = (blockIdx.x << 2) + (threadIdx.x >> 6);
  int lane = threadIdx.x & 63;
  int src  = PERM ? map_row(row) : row;
  float4 v = *reinterpret_cast<const float4*>(xin + (size_t)src * 256 + (lane << 2));
  float s = v.x + v.y + v.z + v.w;
#pragma unroll
  for (int d = 1; d < 64; d <<= 1) s += __shfl_xor(s, d);
  float mean = s * 0.00390625f;
  float ax = v.x - mean, ay = v.y - mean, az = v.z - mean, aw = v.w - mean;
  float s2 = ax * ax + ay * ay + az * az + aw * aw;
#pragma unroll
  for (int d = 1; d < 64; d <<= 1) s2 += __shfl_xor(s2, d);
  float rstd = rsqrtf(s2 * 0.00390625f + 1e-5f);
  float4 gv = *reinterpret_cast<const float4*>(g + (lane << 2));
  float4 bv = *reinterpret_cast<const float4*>(b + (lane << 2));
  bf16x4 o4;
  o4[0] = to_bf16(ax * rstd * gv.x + bv.x);
  o4[1] = to_bf16(ay * rstd * gv.y + bv.y);
  o4[2] = to_bf16(az * rstd * gv.z + bv.z);
  o4[3] = to_bf16(aw * rstd * gv.w + bv.w);
  *reinterpret_cast<bf16x4*>(out + (size_t)row * 256 + (lane << 2)) = o4;
}

// ---------------- bf16 GEMM, B^T weights, 2-phase double-buffered (T3-min) ----------
// 1D grid, XCD chunk-swizzled (T1); nwg % 8 must be 0. NBN = N/128.
// out[m,n] = sum_k A[m,k]*W[n,k] + bias[n]
// EPI 1: GELU(exact) -> bf16        EPI 2: fp32 permuted-row store + resid
// EPI 3: fp32 in-place += (stride 256)
// EPI 4: qkv head-major split: col -> {q,k,v}[h][row][32] bf16
template <int EPI>
__global__ __launch_bounds__(256) void gemm_bt(const bf16_t* __restrict__ A,
                                               const bf16_t* __restrict__ W,
                                               const float* __restrict__ bias,
                                               void* __restrict__ outp,
                                               void* __restrict__ outp2,
                                               void* __restrict__ outp3,
                                               const float* __restrict__ resid,
                                               int M, int N, int K, int NBN) {
  __shared__ __align__(16) bf16_t As[2][128 * 32];
  __shared__ __align__(16) bf16_t Bs[2][128 * 32];
  const int tid  = threadIdx.x;
  const int lane = tid & 63, lo = lane & 15, hi = lane >> 4;
  const int wave = tid >> 6;
  // T1: XCD chunk swizzle (consecutive wg share the A-tile -> same XCD L2)
  const int cpx = gridDim.x >> 3;
  const int wg  = (blockIdx.x & 7) * cpx + (blockIdx.x >> 3);
  const int bn = (wg % NBN) << 7, bm = (wg / NBN) << 7;
  const int wr = (wave >> 1) << 6, wc = (wave & 1) << 6;
  f32x4 acc[4][4] = {};

#define STAGE(buf, kt)                                                     \
  {                                                                        \
    int k0s = (kt) << 5;                                                   \
    _Pragma("unroll") for (int it = 0; it < 2; ++it) {                     \
      int ch = (it << 8) + tid;                                            \
      int r = ch >> 2, kf = (ch & 3) << 3;                                 \
      gload16(A + (size_t)(bm + r) * K + k0s + kf, &As[buf][ch << 3]);     \
      gload16(W + (size_t)(bn + r) * K + k0s + kf, &Bs[buf][ch << 3]);     \
    }                                                                      \
  }

  const int nt = K >> 5;
  STAGE(0, 0);
  __syncthreads();   // drains vmcnt(0): buf0 ready

  for (int t = 0; t < nt; ++t) {
    const int cur = t & 1;
    if (t + 1 < nt) STAGE(cur ^ 1, t + 1);   // prefetch flies under MFMA phase
    bf16x8 af[4], bfr[4];
#pragma unroll
    for (int i = 0; i < 4; ++i)
      af[i] = *reinterpret_cast<const bf16x8*>(&As[cur][(wr + (i << 4) + lo) * 32 + (hi << 3)]);
#pragma unroll
    for (int j = 0; j < 4; ++j)
      bfr[j] = *reinterpret_cast<const bf16x8*>(&Bs[cur][(wc + (j << 4) + lo) * 32 + (hi << 3)]);
#pragma unroll
    for (int i = 0; i < 4; ++i)
#pragma unroll
      for (int j = 0; j < 4; ++j)
        acc[i][j] = mfma16(af[i], bfr[j], acc[i][j]);
    __syncthreads();   // drains prefetch (vmcnt) + protects buf reuse
  }
#undef STAGE

  float bv[4];
#pragma unroll
  for (int j = 0; j < 4; ++j) bv[j] = bias[bn + wc + (j << 4) + lo];

#pragma unroll
  for (int i = 0; i < 4; ++i) {
#pragma unroll
    for (int r = 0; r < 4; ++r) {
      int row = bm + wr + (i << 4) + (hi << 2) + r;
      if constexpr (EPI == 2) {
        int xr = map_row(row);
        float* o = (float*)outp;
#pragma unroll
        for (int j = 0; j < 4; ++j) {
          int col = bn + wc + (j << 4) + lo;
          size_t idx = (size_t)xr * 256 + col;
          o[idx] = resid[idx] + acc[i][j][r] + bv[j];
        }
      } else if constexpr (EPI == 3) {
        float* o = (float*)outp;
#pragma unroll
        for (int j = 0; j < 4; ++j) {
          int col = bn + wc + (j << 4) + lo;
          size_t idx = (size_t)row * 256 + col;
          o[idx] = o[idx] + acc[i][j][r] + bv[j];
        }
      } else if constexpr (EPI == 4) {
#pragma unroll
        for (int j = 0; j < 4; ++j) {
          int col = bn + wc + (j << 4) + lo;   // 0..767
          bf16_t* base = (col < 256) ? (bf16_t*)outp
                        : (col < 512) ? (bf16_t*)outp2 : (bf16_t*)outp3;
          int hd = (col >> 5) & 7, d = col & 31;
          base[((size_t)hd * MROWS + row) * 32 + d] = to_bf16(acc[i][j][r] + bv[j]);
        }
      } else {
        bf16_t* o = (bf16_t*)outp;
#pragma unroll
        for (int j = 0; j < 4; ++j) {
          int col = bn + wc + (j << 4) + lo;
          float v = acc[i][j][r] + bv[j];
          if constexpr (EPI == 1) v = 0.5f * v * (1.0f + erff(v * 0.70710678118654752f));
          o[(size_t)row * N + col] = to_bf16(v);
        }
      }
    }
  }
}

// ---------------- windowed attention: one wave per (window, head)  [proven] ----------
// qh,kh,vh: head-major [8][131072][32] bf16; o: token-major [131072][256] bf16
__global__ __launch_bounds__(256) void attn_kernel(const bf16_t* __restrict__ qh,
                                                   const bf16_t* __restrict__ kh,
                                                   const bf16_t* __restrict__ vh,
                                                   const float* __restrict__ bias,
                                                   bf16_t* __restrict__ o) {
  __shared__ __align__(16) bf16_t Pl[4][64 * 72];
  __shared__ __align__(16) bf16_t Vt[4][32 * 72];
  const int wave = threadIdx.x >> 6, lane = threadIdx.x & 63;
  const int lo = lane & 15, hi = lane >> 4;
  const int id = (blockIdx.x << 2) + wave;  // 0..16383
  const int win = id >> 3, h = id & 7;
  const size_t hb = ((size_t)h * MROWS + (size_t)win * 64) * 32;
  const bf16_t* qb = qh + hb;
  const bf16_t* kb = kh + hb;
  const bf16_t* vb = vh + hb;

  // stage V transposed into LDS: Vt[d][m], stride 72 (coalesced 16B reads)
  const bf16_t* vbl = vb + lane * 32;
#pragma unroll
  for (int c4 = 0; c4 < 4; ++c4) {
    bf16x8 v8 = *reinterpret_cast<const bf16x8*>(vbl + (c4 << 3));
#pragma unroll
    for (int e = 0; e < 8; ++e) Vt[wave][((c4 << 3) + e) * 72 + lane] = v8[e];
  }

  // QK^T (K-dim = 32 = one mfma step); coalesced fragment loads
  bf16x8 qa[4], ka[4];
#pragma unroll
  for (int i = 0; i < 4; ++i)
    qa[i] = *reinterpret_cast<const bf16x8*>(qb + ((i << 4) + lo) * 32 + (hi << 3));
#pragma unroll
  for (int j = 0; j < 4; ++j)
    ka[j] = *reinterpret_cast<const bf16x8*>(kb + ((j << 4) + lo) * 32 + (hi << 3));
  f32x4 s[4][4] = {};
#pragma unroll
  for (int i = 0; i < 4; ++i)
#pragma unroll
    for (int j = 0; j < 4; ++j) s[i][j] = mfma16(qa[i], ka[j], s[i][j]);

  const int wh = (win & 63) >> 3, ww = win & 7;
  const int cls = ((wh == 7) ? 2 : 0) + ((ww == 7) ? 1 : 0);
  const float* bb = bias + ((size_t)cls * 8 + h) * 4096;
  const float scale = 0.17677669529663687f;  // 1/sqrt(32)

  float pinv[4][4];
#pragma unroll
  for (int i = 0; i < 4; ++i) {
#pragma unroll
    for (int r = 0; r < 4; ++r) {
      int n = (i << 4) + (hi << 2) + r;
      const float* brow = bb + n * 64 + lo;
      float vals[4], mx = -1e30f;
#pragma unroll
      for (int j = 0; j < 4; ++j) {
        float val = s[i][j][r] * scale + brow[j << 4];
        vals[j] = val;
        mx = fmaxf(mx, val);
      }
#pragma unroll
      for (int d = 1; d < 16; d <<= 1) mx = fmaxf(mx, __shfl_xor(mx, d));
      float sum = 0.0f;
#pragma unroll
      for (int j = 0; j < 4; ++j) {
        float p = __expf(vals[j] - mx);
        sum += p;
        Pl[wave][n * 72 + (j << 4) + lo] = to_bf16(p);
      }
#pragma unroll
      for (int d = 1; d < 16; d <<= 1) sum += __shfl_xor(sum, d);
      pinv[i][r] = 1.0f / sum;
    }
  }

  __syncthreads();   // Vt + Pl cross-lane LDS visibility

  // PV: O[64,32] = P[64,64] @ V[64,32]
  f32x4 oa[4][2] = {};
#pragma unroll
  for (int kt = 0; kt < 2; ++kt) {
    bf16x8 pa[4], va[2];
#pragma unroll
    for (int i = 0; i < 4; ++i)
      pa[i] = *reinterpret_cast<const bf16x8*>(&Pl[wave][((i << 4) + lo) * 72 + (kt << 5) + (hi << 3)]);
#pragma unroll
    for (int dt = 0; dt < 2; ++dt)
      va[dt] = *reinterpret_cast<const bf16x8*>(&Vt[wave][((dt << 4) + lo) * 72 + (kt << 5) + (hi << 3)]);
#pragma unroll
    for (int i = 0; i < 4; ++i)
#pragma unroll
      for (int dt = 0; dt < 2; ++dt) oa[i][dt] = mfma16(pa[i], va[dt], oa[i][dt]);
  }

  bf16_t* ob = o + (size_t)win * (64 * 256) + h * 32;
#pragma unroll
  for (int i = 0; i < 4; ++i)
#pragma unroll
    for (int r = 0; r < 4; ++r) {
      int n = (i << 4) + (hi << 2) + r;
      float piv = pinv[i][r];
#pragma unroll
      for (int dt = 0; dt < 2; ++dt)
        ob[(size_t)n * 256 + (dt << 4) + lo] = to_bf16(oa[i][dt][r] * piv);
    }
}

// ---------------- launch ----------------
extern "C" void kernel_launch(void* const* d_in, const int* in_sizes, int n_in,
                              void* d_out, int out_size, void* d_ws, size_t ws_size,
                              hipStream_t stream) {
  const float* x      = (const float*)d_in[0];
  const float* n1g    = (const float*)d_in[1];
  const float* n1b    = (const float*)d_in[2];
  const float* qkv_w  = (const float*)d_in[3];
  const float* qkv_b  = (const float*)d_in[4];
  const float* rpbt   = (const float*)d_in[5];
  const float* proj_w = (const float*)d_in[6];
  const float* proj_b = (const float*)d_in[7];
  const float* n2g    = (const float*)d_in[8];
  const float* n2b    = (const float*)d_in[9];
  const float* fc1_w  = (const float*)d_in[10];
  const float* fc1_b  = (const float*)d_in[11];
  const float* fc2_w  = (const float*)d_in[12];
  const float* fc2_b  = (const float*)d_in[13];
  float* out = (float*)d_out;
  char*  ws  = (char*)d_ws;

  // ws: [0,64Mi) hln -> obuf -> h2 chunk | [64Mi,128Mi) qbuf -> x2n | [128Mi..] weights+bias
  // d_out doubles as scratch: k,v bf16 (head-major) until proj, then x2/out fp32.
  const size_t MB64 = 67108864;
  bf16_t* hln  = (bf16_t*)(ws);
  bf16_t* obuf = (bf16_t*)(ws);
  bf16_t* h2   = (bf16_t*)(ws);
  bf16_t* qbuf = (bf16_t*)(ws + MB64);
  bf16_t* x2n  = (bf16_t*)(ws + MB64);
  bf16_t* wb   = (bf16_t*)(ws + 2 * MB64);
  bf16_t* qkv_wb  = wb;                   // 196608 el
  bf16_t* proj_wb = qkv_wb + 196608;      // 65536
  bf16_t* fc1_wb  = proj_wb + 65536;      // 262144
  bf16_t* fc2_wb  = fc1_wb + 262144;      // 262144
  float*  biast   = (float*)(fc2_wb + 262144);  // 131072 f32 = 512KB
  bf16_t* kbuf = (bf16_t*)d_out;          // 33554432 el (64MiB)
  bf16_t* vbuf = kbuf + 33554432;

  cvt_all<<<3072, 256, 0, stream>>>(qkv_w, proj_w, fc1_w, fc2_w,
                                    qkv_wb, proj_wb, fc1_wb, fc2_wb);
  bias_kernel<<<512, 256, 0, stream>>>(rpbt, biast);

  // LN1 + shift + window partition
  ln_kernel<true><<<32768, 256, 0, stream>>>(x, n1g, n1b, hln);

  // fused QKV -> head-major q/k/v (nwg = 6144, %8==0)
  gemm_bt<4><<<6144, 256, 0, stream>>>(hln, qkv_wb, qkv_b, qbuf, kbuf, vbuf,
                                       nullptr, MROWS, 768, 256, 6);

  // windowed attention
  attn_kernel<<<4096, 256, 0, stream>>>(qbuf, kbuf, vbuf, biast, obuf);

  // proj + window-reverse + unshift + residual -> x2 fp32 in d_out (nwg = 2048)
  gemm_bt<2><<<2048, 256, 0, stream>>>(obuf, proj_wb, proj_b, out, nullptr, nullptr,
                                       x, MROWS, 256, 256, 2);

  // LN2
  ln_kernel<false><<<32768, 256, 0, stream>>>(out, n2g, n2b, x2n);

  // MLP in 4 row-chunks (h2 chunk = 32768 x 1024 bf16 = 64MB, L3-resident)
  for (int c = 0; c < 4; ++c) {
    const bf16_t* xa = x2n + (size_t)c * 32768 * 256;
    gemm_bt<1><<<2048, 256, 0, stream>>>(xa, fc1_wb, fc1_b, h2, nullptr, nullptr,
                                         nullptr, 32768, 1024, 256, 8);
    gemm_bt<3><<<512, 256, 0, stream>>>(h2, fc2_wb, fc2_b, out + (size_t)c * 32768 * 256,
                                        nullptr, nullptr, nullptr, 32768, 256, 1024, 2);
  }
}

// Round 7
// 665.110 us; speedup vs baseline: 1.7570x; 1.0043x over previous
//
#include <hip/hip_runtime.h>
#include <hip/hip_bf16.h>
#include <stdint.h>

typedef __bf16 bf16_t;
typedef __bf16 bf16x8 __attribute__((ext_vector_type(8)));
typedef __bf16 bf16x4 __attribute__((ext_vector_type(4)));
typedef float f32x4 __attribute__((ext_vector_type(4)));

// Problem constants: B=32, H=W=64, C=256, heads=8, ws=8, ss=4
#define MROWS 131072   // B * 64 * 64 tokens (window layout rows)

__device__ __forceinline__ bf16_t to_bf16(float f) {
  __hip_bfloat16 h = __float2bfloat16(f);   // RNE
  return *reinterpret_cast<bf16_t*>(&h);
}

__device__ __forceinline__ f32x4 mfma16(bf16x8 a, bf16x8 b, f32x4 c) {
  return __builtin_amdgcn_mfma_f32_16x16x32_bf16(a, b, c, 0, 0, 0);
}

__device__ __forceinline__ void gload16(const void* g, void* l) {
  __builtin_amdgcn_global_load_lds(
      (const __attribute__((address_space(1))) void*)g,
      (__attribute__((address_space(3))) void*)l, 16, 0, 0);
}

// window-layout row m  ->  x row (shift+partition gather; reverse+unshift scatter)
__device__ __forceinline__ int map_row(int m) {
  int b   = m >> 12;
  int rem = m & 4095;
  int win = rem >> 6;
  int n   = rem & 63;
  int gh  = ((win >> 3) << 3) + (n >> 3);
  int gw  = ((win & 7) << 3) + (n & 7);
  int sh  = (gh + 4) & 63;
  int sw  = (gw + 4) & 63;
  return (b << 12) + (sh << 6) + sw;
}

// ---------------- fp32 -> bf16 weight convert (all 4 weight mats, one launch) ------
__global__ __launch_bounds__(256) void cvt_all(const float* __restrict__ qkv_w,
                                               const float* __restrict__ proj_w,
                                               const float* __restrict__ fc1_w,
                                               const float* __restrict__ fc2_w,
                                               bf16_t* __restrict__ qkv_o,
                                               bf16_t* __restrict__ proj_o,
                                               bf16_t* __restrict__ fc1_o,
                                               bf16_t* __restrict__ fc2_o) {
  int i = blockIdx.x * 256 + threadIdx.x;   // 0 .. 786431
  if (i < 196608)       qkv_o[i] = to_bf16(qkv_w[i]);
  else if (i < 262144)  proj_o[i - 196608] = to_bf16(proj_w[i - 196608]);
  else if (i < 524288)  fc1_o[i - 262144] = to_bf16(fc1_w[i - 262144]);
  else                  fc2_o[i - 524288] = to_bf16(fc2_w[i - 524288]);
}

// ---------------- bias table: bias[cls][h][n][m] = rpb(n,m,h) + mask(cls,n,m) ------
__global__ __launch_bounds__(256) void bias_kernel(const float* __restrict__ rpbt,
                                                   float* __restrict__ bias) {
  int idx = blockIdx.x * 256 + threadIdx.x;   // 0 .. 131071
  int m = idx & 63, n = (idx >> 6) & 63, h = (idx >> 12) & 7, c = idx >> 15;
  int yn = n >> 3, xn = n & 7, ym = m >> 3, xm = m & 7;
  float v = rpbt[((yn - ym + 7) * 15 + (xn - xm + 7)) * 8 + h];
  int rn = (c & 2) ? (yn < 4 ? 1 : 2) : 0;
  int cn = (c & 1) ? (xn < 4 ? 1 : 2) : 0;
  int rm = (c & 2) ? (ym < 4 ? 1 : 2) : 0;
  int cm = (c & 1) ? (xm < 4 ? 1 : 2) : 0;
  if (rn * 3 + cn != rm * 3 + cm) v -= 100.0f;
  bias[idx] = v;
}

// ---------------- LayerNorm (wave per row), optional row-permuted gather ----------------
template <bool PERM>
__global__ __launch_bounds__(256) void ln_kernel(const float* __restrict__ xin,
                                                 const float* __restrict__ g,
                                                 const float* __restrict__ b,
                                                 bf16_t* __restrict__ out) {
  int row  = (blockIdx.x << 2) + (threadIdx.x >> 6);
  int lane = threadIdx.x & 63;
  int src  = PERM ? map_row(row) : row;
  float4 v = *reinterpret_cast<const float4*>(xin + (size_t)src * 256 + (lane << 2));
  float s = v.x + v.y + v.z + v.w;
#pragma unroll
  for (int d = 1; d < 64; d <<= 1) s += __shfl_xor(s, d);
  float mean = s * 0.00390625f;
  float ax = v.x - mean, ay = v.y - mean, az = v.z - mean, aw = v.w - mean;
  float s2 = ax * ax + ay * ay + az * az + aw * aw;
#pragma unroll
  for (int d = 1; d < 64; d <<= 1) s2 += __shfl_xor(s2, d);
  float rstd = rsqrtf(s2 * 0.00390625f + 1e-5f);
  float4 gv = *reinterpret_cast<const float4*>(g + (lane << 2));
  float4 bv = *reinterpret_cast<const float4*>(b + (lane << 2));
  bf16x4 o4;
  o4[0] = to_bf16(ax * rstd * gv.x + bv.x);
  o4[1] = to_bf16(ay * rstd * gv.y + bv.y);
  o4[2] = to_bf16(az * rstd * gv.z + bv.z);
  o4[3] = to_bf16(aw * rstd * gv.w + bv.w);
  *reinterpret_cast<bf16x4*>(out + (size_t)row * 256 + (lane << 2)) = o4;
}

// ---------------- bf16 GEMM, B^T weights, 3-stage counted-vmcnt pipeline (T4) -------
// Triple-buffered LDS; tiles t+1, t+2 always in flight while computing t.
// Raw s_barrier + inline s_waitcnt vmcnt(4) -- never drain to 0 in steady state.
// 1D grid, XCD chunk-swizzled (T1); nwg % 8 == 0. NBN = N/128.
// EPI 1: GELU(exact) -> bf16        EPI 2: fp32 permuted-row store + resid
// EPI 3: fp32 in-place += (stride 256)
// EPI 4: qkv head-major split: col -> {q,k,v}[h][row][32] bf16
template <int EPI>
__global__ __launch_bounds__(256) void gemm_bt(const bf16_t* __restrict__ A,
                                               const bf16_t* __restrict__ W,
                                               const float* __restrict__ bias,
                                               void* __restrict__ outp,
                                               void* __restrict__ outp2,
                                               void* __restrict__ outp3,
                                               const float* __restrict__ resid,
                                               int M, int N, int K, int NBN) {
  __shared__ __align__(16) bf16_t As[3 * 128 * 32];
  __shared__ __align__(16) bf16_t Bs[3 * 128 * 32];
  const int tid  = threadIdx.x;
  const int lane = tid & 63, lo = lane & 15, hi = lane >> 4;
  const int wave = tid >> 6;
  // T1: XCD chunk swizzle (consecutive wg share the A-tile -> same XCD L2)
  const int cpx = gridDim.x >> 3;
  const int wg  = (blockIdx.x & 7) * cpx + (blockIdx.x >> 3);
  const int bn = (wg % NBN) << 7, bm = (wg / NBN) << 7;
  const int wr = (wave >> 1) << 6, wc = (wave & 1) << 6;
  f32x4 acc[4][4] = {};

  // one STAGE = 4 gload_lds per thread (2 for A-tile, 2 for B-tile)
#define STAGE(buf, kt)                                                         \
  {                                                                            \
    int k0s = (kt) << 5;                                                       \
    _Pragma("unroll") for (int it = 0; it < 2; ++it) {                         \
      int ch = (it << 8) + tid;                                                \
      int r = ch >> 2, kf = (ch & 3) << 3;                                     \
      gload16(A + (size_t)(bm + r) * K + k0s + kf, &As[((buf) << 12) + (ch << 3)]); \
      gload16(W + (size_t)(bn + r) * K + k0s + kf, &Bs[((buf) << 12) + (ch << 3)]); \
    }                                                                          \
  }

  const int nt = K >> 5;              // 8 or 32 K-steps
  STAGE(0, 0);
  STAGE(1, 1);                        // 8 loads/thread outstanding

  int cb = 0;                         // compute-buffer for tile t
  for (int t = 0; t < nt; ++t) {
    // retire tile t's 4 loads; keep tiles t+1 (and t+2 after stage) in flight
    if (t + 1 < nt) { asm volatile("s_waitcnt vmcnt(4)" ::: "memory"); }
    else            { asm volatile("s_waitcnt vmcnt(0)" ::: "memory"); }
    __builtin_amdgcn_s_barrier();     // tile t ready everywhere; buf[t-1] reads done
    if (t + 2 < nt) {
      int sb = (cb == 0) ? 2 : cb - 1;   // (cb+2)%3 -- overwrites buf used at t-1
      STAGE(sb, t + 2);
    }
    const bf16_t* as = &As[cb << 12];
    const bf16_t* bs = &Bs[cb << 12];
    bf16x8 af[4], bfr[4];
#pragma unroll
    for (int i = 0; i < 4; ++i)
      af[i] = *reinterpret_cast<const bf16x8*>(&as[(wr + (i << 4) + lo) * 32 + (hi << 3)]);
#pragma unroll
    for (int j = 0; j < 4; ++j)
      bfr[j] = *reinterpret_cast<const bf16x8*>(&bs[(wc + (j << 4) + lo) * 32 + (hi << 3)]);
#pragma unroll
    for (int i = 0; i < 4; ++i)
#pragma unroll
      for (int j = 0; j < 4; ++j)
        acc[i][j] = mfma16(af[i], bfr[j], acc[i][j]);
    cb = (cb == 2) ? 0 : cb + 1;
  }
#undef STAGE

  float bv[4];
#pragma unroll
  for (int j = 0; j < 4; ++j) bv[j] = bias[bn + wc + (j << 4) + lo];

#pragma unroll
  for (int i = 0; i < 4; ++i) {
#pragma unroll
    for (int r = 0; r < 4; ++r) {
      int row = bm + wr + (i << 4) + (hi << 2) + r;
      if constexpr (EPI == 2) {
        int xr = map_row(row);
        float* o = (float*)outp;
#pragma unroll
        for (int j = 0; j < 4; ++j) {
          int col = bn + wc + (j << 4) + lo;
          size_t idx = (size_t)xr * 256 + col;
          o[idx] = resid[idx] + acc[i][j][r] + bv[j];
        }
      } else if constexpr (EPI == 3) {
        float* o = (float*)outp;
#pragma unroll
        for (int j = 0; j < 4; ++j) {
          int col = bn + wc + (j << 4) + lo;
          size_t idx = (size_t)row * 256 + col;
          o[idx] = o[idx] + acc[i][j][r] + bv[j];
        }
      } else if constexpr (EPI == 4) {
#pragma unroll
        for (int j = 0; j < 4; ++j) {
          int col = bn + wc + (j << 4) + lo;   // 0..767
          bf16_t* base = (col < 256) ? (bf16_t*)outp
                        : (col < 512) ? (bf16_t*)outp2 : (bf16_t*)outp3;
          int hd = (col >> 5) & 7, d = col & 31;
          base[((size_t)hd * MROWS + row) * 32 + d] = to_bf16(acc[i][j][r] + bv[j]);
        }
      } else {
        bf16_t* o = (bf16_t*)outp;
#pragma unroll
        for (int j = 0; j < 4; ++j) {
          int col = bn + wc + (j << 4) + lo;
          float v = acc[i][j][r] + bv[j];
          if constexpr (EPI == 1) v = 0.5f * v * (1.0f + erff(v * 0.70710678118654752f));
          o[(size_t)row * N + col] = to_bf16(v);
        }
      }
    }
  }
}

// ---------------- windowed attention: one wave per (window, head)  [proven] ----------
// qh,kh,vh: head-major [8][131072][32] bf16; o: token-major [131072][256] bf16
__global__ __launch_bounds__(256) void attn_kernel(const bf16_t* __restrict__ qh,
                                                   const bf16_t* __restrict__ kh,
                                                   const bf16_t* __restrict__ vh,
                                                   const float* __restrict__ bias,
                                                   bf16_t* __restrict__ o) {
  __shared__ __align__(16) bf16_t Pl[4][64 * 72];
  __shared__ __align__(16) bf16_t Vt[4][32 * 72];
  const int wave = threadIdx.x >> 6, lane = threadIdx.x & 63;
  const int lo = lane & 15, hi = lane >> 4;
  const int id = (blockIdx.x << 2) + wave;  // 0..16383
  const int win = id >> 3, h = id & 7;
  const size_t hb = ((size_t)h * MROWS + (size_t)win * 64) * 32;
  const bf16_t* qb = qh + hb;
  const bf16_t* kb = kh + hb;
  const bf16_t* vb = vh + hb;

  // stage V transposed into LDS: Vt[d][m], stride 72 (coalesced 16B reads)
  const bf16_t* vbl = vb + lane * 32;
#pragma unroll
  for (int c4 = 0; c4 < 4; ++c4) {
    bf16x8 v8 = *reinterpret_cast<const bf16x8*>(vbl + (c4 << 3));
#pragma unroll
    for (int e = 0; e < 8; ++e) Vt[wave][((c4 << 3) + e) * 72 + lane] = v8[e];
  }

  // QK^T (K-dim = 32 = one mfma step); coalesced fragment loads
  bf16x8 qa[4], ka[4];
#pragma unroll
  for (int i = 0; i < 4; ++i)
    qa[i] = *reinterpret_cast<const bf16x8*>(qb + ((i << 4) + lo) * 32 + (hi << 3));
#pragma unroll
  for (int j = 0; j < 4; ++j)
    ka[j] = *reinterpret_cast<const bf16x8*>(kb + ((j << 4) + lo) * 32 + (hi << 3));
  f32x4 s[4][4] = {};
#pragma unroll
  for (int i = 0; i < 4; ++i)
#pragma unroll
    for (int j = 0; j < 4; ++j) s[i][j] = mfma16(qa[i], ka[j], s[i][j]);

  const int wh = (win & 63) >> 3, ww = win & 7;
  const int cls = ((wh == 7) ? 2 : 0) + ((ww == 7) ? 1 : 0);
  const float* bb = bias + ((size_t)cls * 8 + h) * 4096;
  const float scale = 0.17677669529663687f;  // 1/sqrt(32)

  float pinv[4][4];
#pragma unroll
  for (int i = 0; i < 4; ++i) {
#pragma unroll
    for (int r = 0; r < 4; ++r) {
      int n = (i << 4) + (hi << 2) + r;
      const float* brow = bb + n * 64 + lo;
      float vals[4], mx = -1e30f;
#pragma unroll
      for (int j = 0; j < 4; ++j) {
        float val = s[i][j][r] * scale + brow[j << 4];
        vals[j] = val;
        mx = fmaxf(mx, val);
      }
#pragma unroll
      for (int d = 1; d < 16; d <<= 1) mx = fmaxf(mx, __shfl_xor(mx, d));
      float sum = 0.0f;
#pragma unroll
      for (int j = 0; j < 4; ++j) {
        float p = __expf(vals[j] - mx);
        sum += p;
        Pl[wave][n * 72 + (j << 4) + lo] = to_bf16(p);
      }
#pragma unroll
      for (int d = 1; d < 16; d <<= 1) sum += __shfl_xor(sum, d);
      pinv[i][r] = 1.0f / sum;
    }
  }

  __syncthreads();   // Vt + Pl cross-lane LDS visibility

  // PV: O[64,32] = P[64,64] @ V[64,32]
  f32x4 oa[4][2] = {};
#pragma unroll
  for (int kt = 0; kt < 2; ++kt) {
    bf16x8 pa[4], va[2];
#pragma unroll
    for (int i = 0; i < 4; ++i)
      pa[i] = *reinterpret_cast<const bf16x8*>(&Pl[wave][((i << 4) + lo) * 72 + (kt << 5) + (hi << 3)]);
#pragma unroll
    for (int dt = 0; dt < 2; ++dt)
      va[dt] = *reinterpret_cast<const bf16x8*>(&Vt[wave][((dt << 4) + lo) * 72 + (kt << 5) + (hi << 3)]);
#pragma unroll
    for (int i = 0; i < 4; ++i)
#pragma unroll
      for (int dt = 0; dt < 2; ++dt) oa[i][dt] = mfma16(pa[i], va[dt], oa[i][dt]);
  }

  bf16_t* ob = o + (size_t)win * (64 * 256) + h * 32;
#pragma unroll
  for (int i = 0; i < 4; ++i)
#pragma unroll
    for (int r = 0; r < 4; ++r) {
      int n = (i << 4) + (hi << 2) + r;
      float piv = pinv[i][r];
#pragma unroll
      for (int dt = 0; dt < 2; ++dt)
        ob[(size_t)n * 256 + (dt << 4) + lo] = to_bf16(oa[i][dt][r] * piv);
    }
}

// ---------------- launch ----------------
extern "C" void kernel_launch(void* const* d_in, const int* in_sizes, int n_in,
                              void* d_out, int out_size, void* d_ws, size_t ws_size,
                              hipStream_t stream) {
  const float* x      = (const float*)d_in[0];
  const float* n1g    = (const float*)d_in[1];
  const float* n1b    = (const float*)d_in[2];
  const float* qkv_w  = (const float*)d_in[3];
  const float* qkv_b  = (const float*)d_in[4];
  const float* rpbt   = (const float*)d_in[5];
  const float* proj_w = (const float*)d_in[6];
  const float* proj_b = (const float*)d_in[7];
  const float* n2g    = (const float*)d_in[8];
  const float* n2b    = (const float*)d_in[9];
  const float* fc1_w  = (const float*)d_in[10];
  const float* fc1_b  = (const float*)d_in[11];
  const float* fc2_w  = (const float*)d_in[12];
  const float* fc2_b  = (const float*)d_in[13];
  float* out = (float*)d_out;
  char*  ws  = (char*)d_ws;

  // ws: [0,64Mi) hln -> obuf -> h2 chunk | [64Mi,128Mi) qbuf -> x2n | [128Mi..] weights+bias
  // d_out doubles as scratch: k,v bf16 (head-major) until proj, then x2/out fp32.
  const size_t MB64 = 67108864;
  bf16_t* hln  = (bf16_t*)(ws);
  bf16_t* obuf = (bf16_t*)(ws);
  bf16_t* h2   = (bf16_t*)(ws);
  bf16_t* qbuf = (bf16_t*)(ws + MB64);
  bf16_t* x2n  = (bf16_t*)(ws + MB64);
  bf16_t* wb   = (bf16_t*)(ws + 2 * MB64);
  bf16_t* qkv_wb  = wb;                   // 196608 el
  bf16_t* proj_wb = qkv_wb + 196608;      // 65536
  bf16_t* fc1_wb  = proj_wb + 65536;      // 262144
  bf16_t* fc2_wb  = fc1_wb + 262144;      // 262144
  float*  biast   = (float*)(fc2_wb + 262144);  // 131072 f32 = 512KB
  bf16_t* kbuf = (bf16_t*)d_out;          // 33554432 el (64MiB)
  bf16_t* vbuf = kbuf + 33554432;

  cvt_all<<<3072, 256, 0, stream>>>(qkv_w, proj_w, fc1_w, fc2_w,
                                    qkv_wb, proj_wb, fc1_wb, fc2_wb);
  bias_kernel<<<512, 256, 0, stream>>>(rpbt, biast);

  // LN1 + shift + window partition
  ln_kernel<true><<<32768, 256, 0, stream>>>(x, n1g, n1b, hln);

  // fused QKV -> head-major q/k/v (nwg = 6144, %8==0)
  gemm_bt<4><<<6144, 256, 0, stream>>>(hln, qkv_wb, qkv_b, qbuf, kbuf, vbuf,
                                       nullptr, MROWS, 768, 256, 6);

  // windowed attention
  attn_kernel<<<4096, 256, 0, stream>>>(qbuf, kbuf, vbuf, biast, obuf);

  // proj + window-reverse + unshift + residual -> x2 fp32 in d_out (nwg = 2048)
  gemm_bt<2><<<2048, 256, 0, stream>>>(obuf, proj_wb, proj_b, out, nullptr, nullptr,
                                       x, MROWS, 256, 256, 2);

  // LN2
  ln_kernel<false><<<32768, 256, 0, stream>>>(out, n2g, n2b, x2n);

  // MLP in 4 row-chunks (h2 chunk = 32768 x 1024 bf16 = 64MB, L3-resident)
  for (int c = 0; c < 4; ++c) {
    const bf16_t* xa = x2n + (size_t)c * 32768 * 256;
    gemm_bt<1><<<2048, 256, 0, stream>>>(xa, fc1_wb, fc1_b, h2, nullptr, nullptr,
                                         nullptr, 32768, 1024, 256, 8);
    gemm_bt<3><<<512, 256, 0, stream>>>(h2, fc2_wb, fc2_b, out + (size_t)c * 32768 * 256,
                                        nullptr, nullptr, nullptr, 32768, 256, 1024, 2);
  }
}

// Round 8
// 656.829 us; speedup vs baseline: 1.7791x; 1.0126x over previous
//
#include <hip/hip_runtime.h>
#include <hip/hip_bf16.h>
#include <stdint.h>

typedef __bf16 bf16_t;
typedef __bf16 bf16x8 __attribute__((ext_vector_type(8)));
typedef __bf16 bf16x4 __attribute__((ext_vector_type(4)));
typedef float f32x4 __attribute__((ext_vector_type(4)));

// Problem constants: B=32, H=W=64, C=256, heads=8, ws=8, ss=4
#define MROWS 131072   // B * 64 * 64 tokens (window layout rows)

__device__ __forceinline__ bf16_t to_bf16(float f) {
  __hip_bfloat16 h = __float2bfloat16(f);   // RNE
  return *reinterpret_cast<bf16_t*>(&h);
}

__device__ __forceinline__ f32x4 mfma16(bf16x8 a, bf16x8 b, f32x4 c) {
  return __builtin_amdgcn_mfma_f32_16x16x32_bf16(a, b, c, 0, 0, 0);
}

__device__ __forceinline__ void gload16(const void* g, void* l) {
  __builtin_amdgcn_global_load_lds(
      (const __attribute__((address_space(1))) void*)g,
      (__attribute__((address_space(3))) void*)l, 16, 0, 0);
}

// window-layout row m  ->  x row (shift+partition gather; reverse+unshift scatter)
__device__ __forceinline__ int map_row(int m) {
  int b   = m >> 12;
  int rem = m & 4095;
  int win = rem >> 6;
  int n   = rem & 63;
  int gh  = ((win >> 3) << 3) + (n >> 3);
  int gw  = ((win & 7) << 3) + (n & 7);
  int sh  = (gh + 4) & 63;
  int sw  = (gw + 4) & 63;
  return (b << 12) + (sh << 6) + sw;
}

// ---------------- fp32 -> bf16 weight convert (all 4 weight mats, one launch) ------
__global__ __launch_bounds__(256) void cvt_all(const float* __restrict__ qkv_w,
                                               const float* __restrict__ proj_w,
                                               const float* __restrict__ fc1_w,
                                               const float* __restrict__ fc2_w,
                                               bf16_t* __restrict__ qkv_o,
                                               bf16_t* __restrict__ proj_o,
                                               bf16_t* __restrict__ fc1_o,
                                               bf16_t* __restrict__ fc2_o) {
  int i = blockIdx.x * 256 + threadIdx.x;   // 0 .. 786431
  if (i < 196608)       qkv_o[i] = to_bf16(qkv_w[i]);
  else if (i < 262144)  proj_o[i - 196608] = to_bf16(proj_w[i - 196608]);
  else if (i < 524288)  fc1_o[i - 262144] = to_bf16(fc1_w[i - 262144]);
  else                  fc2_o[i - 524288] = to_bf16(fc2_w[i - 524288]);
}

// ---------------- bias table: bias[cls][h][n][m] = rpb(n,m,h) + mask(cls,n,m) ------
__global__ __launch_bounds__(256) void bias_kernel(const float* __restrict__ rpbt,
                                                   float* __restrict__ bias) {
  int idx = blockIdx.x * 256 + threadIdx.x;   // 0 .. 131071
  int m = idx & 63, n = (idx >> 6) & 63, h = (idx >> 12) & 7, c = idx >> 15;
  int yn = n >> 3, xn = n & 7, ym = m >> 3, xm = m & 7;
  float v = rpbt[((yn - ym + 7) * 15 + (xn - xm + 7)) * 8 + h];
  int rn = (c & 2) ? (yn < 4 ? 1 : 2) : 0;
  int cn = (c & 1) ? (xn < 4 ? 1 : 2) : 0;
  int rm = (c & 2) ? (ym < 4 ? 1 : 2) : 0;
  int cm = (c & 1) ? (xm < 4 ? 1 : 2) : 0;
  if (rn * 3 + cn != rm * 3 + cm) v -= 100.0f;
  bias[idx] = v;
}

// ---------------- LayerNorm (wave per row), optional row-permuted gather ----------------
template <bool PERM>
__global__ __launch_bounds__(256) void ln_kernel(const float* __restrict__ xin,
                                                 const float* __restrict__ g,
                                                 const float* __restrict__ b,
                                                 bf16_t* __restrict__ out) {
  int row  = (blockIdx.x << 2) + (threadIdx.x >> 6);
  int lane = threadIdx.x & 63;
  int src  = PERM ? map_row(row) : row;
  float4 v = *reinterpret_cast<const float4*>(xin + (size_t)src * 256 + (lane << 2));
  float s = v.x + v.y + v.z + v.w;
#pragma unroll
  for (int d = 1; d < 64; d <<= 1) s += __shfl_xor(s, d);
  float mean = s * 0.00390625f;
  float ax = v.x - mean, ay = v.y - mean, az = v.z - mean, aw = v.w - mean;
  float s2 = ax * ax + ay * ay + az * az + aw * aw;
#pragma unroll
  for (int d = 1; d < 64; d <<= 1) s2 += __shfl_xor(s2, d);
  float rstd = rsqrtf(s2 * 0.00390625f + 1e-5f);
  float4 gv = *reinterpret_cast<const float4*>(g + (lane << 2));
  float4 bv = *reinterpret_cast<const float4*>(b + (lane << 2));
  bf16x4 o4;
  o4[0] = to_bf16(ax * rstd * gv.x + bv.x);
  o4[1] = to_bf16(ay * rstd * gv.y + bv.y);
  o4[2] = to_bf16(az * rstd * gv.z + bv.z);
  o4[3] = to_bf16(aw * rstd * gv.w + bv.w);
  *reinterpret_cast<bf16x4*>(out + (size_t)row * 256 + (lane << 2)) = o4;
}

// ---------------- bf16 GEMM, B^T weights, 3-stage counted-vmcnt pipeline (T4) -------
// + T2 bank-conflict swizzle (pre-swizzled SOURCE + swizzled ds_read; LDS linear)
// + T5 setprio around the MFMA cluster.
// Swizzle: K-chunk kf (16B) of row r lives at linear slot kf ^ ((r>>1)&3).
//   Read slot = (r&1)*4 + (hi ^ ((r>>1)&3)) covers the 8 16B-slots of a 128B
//   bank-line 2-to-1 over 16 lanes -> 2-way aliasing = free (m136).
// 1D grid, XCD chunk-swizzled (T1); nwg % 8 == 0. NBN = N/128.
// EPI 1: GELU(exact) -> bf16        EPI 2: fp32 permuted-row store + resid
// EPI 3: fp32 in-place += (stride 256)
// EPI 4: qkv head-major split: col -> {q,k,v}[h][row][32] bf16
template <int EPI>
__global__ __launch_bounds__(256) void gemm_bt(const bf16_t* __restrict__ A,
                                               const bf16_t* __restrict__ W,
                                               const float* __restrict__ bias,
                                               void* __restrict__ outp,
                                               void* __restrict__ outp2,
                                               void* __restrict__ outp3,
                                               const float* __restrict__ resid,
                                               int M, int N, int K, int NBN) {
  __shared__ __align__(16) bf16_t As[3 * 128 * 32];
  __shared__ __align__(16) bf16_t Bs[3 * 128 * 32];
  const int tid  = threadIdx.x;
  const int lane = tid & 63, lo = lane & 15, hi = lane >> 4;
  const int wave = tid >> 6;
  // T1: XCD chunk swizzle (consecutive wg share the A-tile -> same XCD L2)
  const int cpx = gridDim.x >> 3;
  const int wg  = (blockIdx.x & 7) * cpx + (blockIdx.x >> 3);
  const int bn = (wg % NBN) << 7, bm = (wg / NBN) << 7;
  const int wr = (wave >> 1) << 6, wc = (wave & 1) << 6;
  f32x4 acc[4][4] = {};

  // one STAGE = 4 gload_lds per thread; SOURCE K-chunk pre-swizzled (T2, rule #21)
#define STAGE(buf, kt)                                                         \
  {                                                                            \
    int k0s = (kt) << 5;                                                       \
    _Pragma("unroll") for (int it = 0; it < 2; ++it) {                         \
      int ch = (it << 8) + tid;                                                \
      int r = ch >> 2;                                                         \
      int kf = ((ch & 3) ^ ((r >> 1) & 3)) << 3;                               \
      gload16(A + (size_t)(bm + r) * K + k0s + kf, &As[((buf) << 12) + (ch << 3)]); \
      gload16(W + (size_t)(bn + r) * K + k0s + kf, &Bs[((buf) << 12) + (ch << 3)]); \
    }                                                                          \
  }

  const int nt = K >> 5;              // 8 or 32 K-steps
  STAGE(0, 0);
  STAGE(1, 1);                        // 8 loads/thread outstanding

  int cb = 0;                         // compute-buffer for tile t
  for (int t = 0; t < nt; ++t) {
    // retire tile t's 4 loads; keep tiles t+1 (and t+2 after stage) in flight
    if (t + 1 < nt) { asm volatile("s_waitcnt vmcnt(4)" ::: "memory"); }
    else            { asm volatile("s_waitcnt vmcnt(0)" ::: "memory"); }
    __builtin_amdgcn_s_barrier();     // tile t ready everywhere; buf[t-1] reads done
    if (t + 2 < nt) {
      int sb = (cb == 0) ? 2 : cb - 1;   // (cb+2)%3 -- overwrites buf used at t-1
      STAGE(sb, t + 2);
    }
    const bf16_t* as = &As[cb << 12];
    const bf16_t* bs = &Bs[cb << 12];
    bf16x8 af[4], bfr[4];
#pragma unroll
    for (int i = 0; i < 4; ++i) {
      int ra = wr + (i << 4) + lo;
      af[i] = *reinterpret_cast<const bf16x8*>(&as[ra * 32 + ((hi ^ ((ra >> 1) & 3)) << 3)]);
    }
#pragma unroll
    for (int j = 0; j < 4; ++j) {
      int rb = wc + (j << 4) + lo;
      bfr[j] = *reinterpret_cast<const bf16x8*>(&bs[rb * 32 + ((hi ^ ((rb >> 1) & 3)) << 3)]);
    }
    __builtin_amdgcn_s_setprio(1);    // T5: favor MFMA-issuing wave
#pragma unroll
    for (int i = 0; i < 4; ++i)
#pragma unroll
      for (int j = 0; j < 4; ++j)
        acc[i][j] = mfma16(af[i], bfr[j], acc[i][j]);
    __builtin_amdgcn_s_setprio(0);
    cb = (cb == 2) ? 0 : cb + 1;
  }
#undef STAGE

  float bv[4];
#pragma unroll
  for (int j = 0; j < 4; ++j) bv[j] = bias[bn + wc + (j << 4) + lo];

#pragma unroll
  for (int i = 0; i < 4; ++i) {
#pragma unroll
    for (int r = 0; r < 4; ++r) {
      int row = bm + wr + (i << 4) + (hi << 2) + r;
      if constexpr (EPI == 2) {
        int xr = map_row(row);
        float* o = (float*)outp;
#pragma unroll
        for (int j = 0; j < 4; ++j) {
          int col = bn + wc + (j << 4) + lo;
          size_t idx = (size_t)xr * 256 + col;
          o[idx] = resid[idx] + acc[i][j][r] + bv[j];
        }
      } else if constexpr (EPI == 3) {
        float* o = (float*)outp;
#pragma unroll
        for (int j = 0; j < 4; ++j) {
          int col = bn + wc + (j << 4) + lo;
          size_t idx = (size_t)row * 256 + col;
          o[idx] = o[idx] + acc[i][j][r] + bv[j];
        }
      } else if constexpr (EPI == 4) {
#pragma unroll
        for (int j = 0; j < 4; ++j) {
          int col = bn + wc + (j << 4) + lo;   // 0..767
          bf16_t* base = (col < 256) ? (bf16_t*)outp
                        : (col < 512) ? (bf16_t*)outp2 : (bf16_t*)outp3;
          int hd = (col >> 5) & 7, d = col & 31;
          base[((size_t)hd * MROWS + row) * 32 + d] = to_bf16(acc[i][j][r] + bv[j]);
        }
      } else {
        bf16_t* o = (bf16_t*)outp;
#pragma unroll
        for (int j = 0; j < 4; ++j) {
          int col = bn + wc + (j << 4) + lo;
          float v = acc[i][j][r] + bv[j];
          if constexpr (EPI == 1) v = 0.5f * v * (1.0f + erff(v * 0.70710678118654752f));
          o[(size_t)row * N + col] = to_bf16(v);
        }
      }
    }
  }
}

// ---------------- windowed attention: one wave per (window, head)  [proven] ----------
// qh,kh,vh: head-major [8][131072][32] bf16; o: token-major [131072][256] bf16
__global__ __launch_bounds__(256) void attn_kernel(const bf16_t* __restrict__ qh,
                                                   const bf16_t* __restrict__ kh,
                                                   const bf16_t* __restrict__ vh,
                                                   const float* __restrict__ bias,
                                                   bf16_t* __restrict__ o) {
  __shared__ __align__(16) bf16_t Pl[4][64 * 72];
  __shared__ __align__(16) bf16_t Vt[4][32 * 72];
  const int wave = threadIdx.x >> 6, lane = threadIdx.x & 63;
  const int lo = lane & 15, hi = lane >> 4;
  const int id = (blockIdx.x << 2) + wave;  // 0..16383
  const int win = id >> 3, h = id & 7;
  const size_t hb = ((size_t)h * MROWS + (size_t)win * 64) * 32;
  const bf16_t* qb = qh + hb;
  const bf16_t* kb = kh + hb;
  const bf16_t* vb = vh + hb;

  // stage V transposed into LDS: Vt[d][m], stride 72 (coalesced 16B reads)
  const bf16_t* vbl = vb + lane * 32;
#pragma unroll
  for (int c4 = 0; c4 < 4; ++c4) {
    bf16x8 v8 = *reinterpret_cast<const bf16x8*>(vbl + (c4 << 3));
#pragma unroll
    for (int e = 0; e < 8; ++e) Vt[wave][((c4 << 3) + e) * 72 + lane] = v8[e];
  }

  // QK^T (K-dim = 32 = one mfma step); coalesced fragment loads
  bf16x8 qa[4], ka[4];
#pragma unroll
  for (int i = 0; i < 4; ++i)
    qa[i] = *reinterpret_cast<const bf16x8*>(qb + ((i << 4) + lo) * 32 + (hi << 3));
#pragma unroll
  for (int j = 0; j < 4; ++j)
    ka[j] = *reinterpret_cast<const bf16x8*>(kb + ((j << 4) + lo) * 32 + (hi << 3));
  f32x4 s[4][4] = {};
#pragma unroll
  for (int i = 0; i < 4; ++i)
#pragma unroll
    for (int j = 0; j < 4; ++j) s[i][j] = mfma16(qa[i], ka[j], s[i][j]);

  const int wh = (win & 63) >> 3, ww = win & 7;
  const int cls = ((wh == 7) ? 2 : 0) + ((ww == 7) ? 1 : 0);
  const float* bb = bias + ((size_t)cls * 8 + h) * 4096;
  const float scale = 0.17677669529663687f;  // 1/sqrt(32)

  float pinv[4][4];
#pragma unroll
  for (int i = 0; i < 4; ++i) {
#pragma unroll
    for (int r = 0; r < 4; ++r) {
      int n = (i << 4) + (hi << 2) + r;
      const float* brow = bb + n * 64 + lo;
      float vals[4], mx = -1e30f;
#pragma unroll
      for (int j = 0; j < 4; ++j) {
        float val = s[i][j][r] * scale + brow[j << 4];
        vals[j] = val;
        mx = fmaxf(mx, val);
      }
#pragma unroll
      for (int d = 1; d < 16; d <<= 1) mx = fmaxf(mx, __shfl_xor(mx, d));
      float sum = 0.0f;
#pragma unroll
      for (int j = 0; j < 4; ++j) {
        float p = __expf(vals[j] - mx);
        sum += p;
        Pl[wave][n * 72 + (j << 4) + lo] = to_bf16(p);
      }
#pragma unroll
      for (int d = 1; d < 16; d <<= 1) sum += __shfl_xor(sum, d);
      pinv[i][r] = 1.0f / sum;
    }
  }

  __syncthreads();   // Vt + Pl cross-lane LDS visibility

  // PV: O[64,32] = P[64,64] @ V[64,32]
  f32x4 oa[4][2] = {};
#pragma unroll
  for (int kt = 0; kt < 2; ++kt) {
    bf16x8 pa[4], va[2];
#pragma unroll
    for (int i = 0; i < 4; ++i)
      pa[i] = *reinterpret_cast<const bf16x8*>(&Pl[wave][((i << 4) + lo) * 72 + (kt << 5) + (hi << 3)]);
#pragma unroll
    for (int dt = 0; dt < 2; ++dt)
      va[dt] = *reinterpret_cast<const bf16x8*>(&Vt[wave][((dt << 4) + lo) * 72 + (kt << 5) + (hi << 3)]);
#pragma unroll
    for (int i = 0; i < 4; ++i)
#pragma unroll
      for (int dt = 0; dt < 2; ++dt) oa[i][dt] = mfma16(pa[i], va[dt], oa[i][dt]);
  }

  bf16_t* ob = o + (size_t)win * (64 * 256) + h * 32;
#pragma unroll
  for (int i = 0; i < 4; ++i)
#pragma unroll
    for (int r = 0; r < 4; ++r) {
      int n = (i << 4) + (hi << 2) + r;
      float piv = pinv[i][r];
#pragma unroll
      for (int dt = 0; dt < 2; ++dt)
        ob[(size_t)n * 256 + (dt << 4) + lo] = to_bf16(oa[i][dt][r] * piv);
    }
}

// ---------------- launch ----------------
extern "C" void kernel_launch(void* const* d_in, const int* in_sizes, int n_in,
                              void* d_out, int out_size, void* d_ws, size_t ws_size,
                              hipStream_t stream) {
  const float* x      = (const float*)d_in[0];
  const float* n1g    = (const float*)d_in[1];
  const float* n1b    = (const float*)d_in[2];
  const float* qkv_w  = (const float*)d_in[3];
  const float* qkv_b  = (const float*)d_in[4];
  const float* rpbt   = (const float*)d_in[5];
  const float* proj_w = (const float*)d_in[6];
  const float* proj_b = (const float*)d_in[7];
  const float* n2g    = (const float*)d_in[8];
  const float* n2b    = (const float*)d_in[9];
  const float* fc1_w  = (const float*)d_in[10];
  const float* fc1_b  = (const float*)d_in[11];
  const float* fc2_w  = (const float*)d_in[12];
  const float* fc2_b  = (const float*)d_in[13];
  float* out = (float*)d_out;
  char*  ws  = (char*)d_ws;

  // ws: [0,64Mi) hln -> obuf -> h2 chunk | [64Mi,128Mi) qbuf -> x2n | [128Mi..] weights+bias
  // d_out doubles as scratch: k,v bf16 (head-major) until proj, then x2/out fp32.
  const size_t MB64 = 67108864;
  bf16_t* hln  = (bf16_t*)(ws);
  bf16_t* obuf = (bf16_t*)(ws);
  bf16_t* h2   = (bf16_t*)(ws);
  bf16_t* qbuf = (bf16_t*)(ws + MB64);
  bf16_t* x2n  = (bf16_t*)(ws + MB64);
  bf16_t* wb   = (bf16_t*)(ws + 2 * MB64);
  bf16_t* qkv_wb  = wb;                   // 196608 el
  bf16_t* proj_wb = qkv_wb + 196608;      // 65536
  bf16_t* fc1_wb  = proj_wb + 65536;      // 262144
  bf16_t* fc2_wb  = fc1_wb + 262144;      // 262144
  float*  biast   = (float*)(fc2_wb + 262144);  // 131072 f32 = 512KB
  bf16_t* kbuf = (bf16_t*)d_out;          // 33554432 el (64MiB)
  bf16_t* vbuf = kbuf + 33554432;

  cvt_all<<<3072, 256, 0, stream>>>(qkv_w, proj_w, fc1_w, fc2_w,
                                    qkv_wb, proj_wb, fc1_wb, fc2_wb);
  bias_kernel<<<512, 256, 0, stream>>>(rpbt, biast);

  // LN1 + shift + window partition
  ln_kernel<true><<<32768, 256, 0, stream>>>(x, n1g, n1b, hln);

  // fused QKV -> head-major q/k/v (nwg = 6144, %8==0)
  gemm_bt<4><<<6144, 256, 0, stream>>>(hln, qkv_wb, qkv_b, qbuf, kbuf, vbuf,
                                       nullptr, MROWS, 768, 256, 6);

  // windowed attention
  attn_kernel<<<4096, 256, 0, stream>>>(qbuf, kbuf, vbuf, biast, obuf);

  // proj + window-reverse + unshift + residual -> x2 fp32 in d_out (nwg = 2048)
  gemm_bt<2><<<2048, 256, 0, stream>>>(obuf, proj_wb, proj_b, out, nullptr, nullptr,
                                       x, MROWS, 256, 256, 2);

  // LN2
  ln_kernel<false><<<32768, 256, 0, stream>>>(out, n2g, n2b, x2n);

  // MLP in 4 row-chunks (h2 chunk = 32768 x 1024 bf16 = 64MB, L3-resident)
  for (int c = 0; c < 4; ++c) {
    const bf16_t* xa = x2n + (size_t)c * 32768 * 256;
    gemm_bt<1><<<2048, 256, 0, stream>>>(xa, fc1_wb, fc1_b, h2, nullptr, nullptr,
                                         nullptr, 32768, 1024, 256, 8);
    gemm_bt<3><<<512, 256, 0, stream>>>(h2, fc2_wb, fc2_b, out + (size_t)c * 32768 * 256,
                                        nullptr, nullptr, nullptr, 32768, 256, 1024, 2);
  }
}